// Round 3
// baseline (93.954 us; speedup 1.0000x reference)
//
#include <hip/hip_runtime.h>
#include <hip/hip_bf16.h>
#include <hip/hip_cooperative_groups.h>

namespace cg = cooperative_groups;

#define L_ 30
#define NB 2
#define NN 64
#define NM 64
#define MCH 16

// ws float offsets
#define O_BOP  0        // 128
#define O_WEWK 128      // 4x128
#define O_CK   640      // 30x128
#define O_QS   4480     // 128x128 (q / sqrt(dh))
#define O_GT   20864    // ushort[128][168] transposed G, 10752 floats

typedef __attribute__((ext_vector_type(8))) short short8;
typedef __attribute__((ext_vector_type(4))) float f32x4;

__device__ __forceinline__ unsigned short f2b(float v) {
    union { float f; unsigned int u; } x; x.f = v;
    unsigned int u = x.u + 0x7FFFu + ((x.u >> 16) & 1u);
    return (unsigned short)(u >> 16);
}
__device__ __forceinline__ float b2f(unsigned short s) {
    union { unsigned int u; float f; } x; x.u = ((unsigned int)s) << 16; return x.f;
}
__device__ __forceinline__ float dot4(float4 a, float4 b) {
    return a.x*b.x + a.y*b.y + a.z*b.z + a.w*b.w;
}

__global__ __launch_bounds__(256, 2)
void k_fused(const float* __restrict__ agent, const float* __restrict__ lane,
             const float* __restrict__ We,  const float* __restrict__ be,
             const float* __restrict__ Wa,  const float* __restrict__ ba,
             const float* __restrict__ pe,
             const float* __restrict__ Wq,  const float* __restrict__ bq,
             const float* __restrict__ Wk,  const float* __restrict__ bk,
             const float* __restrict__ Wv,  const float* __restrict__ bv,
             const float* __restrict__ Wo,  const float* __restrict__ bo,
             const float* __restrict__ Wp,  const float* __restrict__ bp,
             float* __restrict__ ws, float* __restrict__ out) {

    __shared__ __align__(16) unsigned short G_T[128][168];   // 43008 B (pre scratch overlay)
    __shared__ __align__(16) unsigned short WcB[16][168];    // bf16 Wc (k<16 we4, 16..136 w, pad 0)
    __shared__ __align__(16) float Sc_s[16][124];            // f32 raw scores [m][h*30+l]
    __shared__ __align__(16) unsigned short edge_s[MCH][30][4];
    __shared__ float u_s[16];
    __shared__ float c_s[120];

    const int t = threadIdx.x;
    const int bid = blockIdx.x;

    // ---------------- PRE: blocks 0..127, one output column e each ----------------
    if (bid < 128) {
        const int e = bid;
        float* pb     = (float*)&G_T[0][0];
        float* wp_s   = pb;           // 128
        float* wq_s   = pb + 128;     // 128
        float* wk_s   = pb + 256;     // 128
        float* wop_s  = pb + 384;     // 128
        float* wawq_s = pb + 512;     // 12
        float* misc   = pb + 524;     // [0]=bqq [1..4]=dbv
        float* pesum  = pb + 532;     // 30*132
        float* wvop   = pb + 4492;    // 4*132

        // P0: stage weight columns + pesum
        if (t < 128) { wp_s[t] = Wp[t*128+e]; wq_s[t] = Wq[t*128+e]; }
        else         { int d = t-128; wk_s[d] = Wk[d*128+e]; }
        for (int i = t; i < 30*128; i += 256) {
            int l = i >> 7, d = i & 127;
            pesum[l*132+d] = be[d] + pe[l*128+d];
        }
        __syncthreads();

        // P1: wop_col, Ck, WaWq, bqq, WeWk
        if (t < 128) {
            const float4* wo  = (const float4*)(Wo + t*128);
            const float4* wp4 = (const float4*)wp_s;
            float a = 0.f;
            #pragma unroll 8
            for (int i = 0; i < 32; ++i) a += dot4(wo[i], wp4[i]);
            wop_s[t] = a;
        } else if (t < 158) {
            int l = t - 128;
            const float4* pl  = (const float4*)(pesum + l*132);
            const float4* wk4 = (const float4*)wk_s;
            float a = bk[e];
            #pragma unroll 8
            for (int i = 0; i < 32; ++i) a += dot4(pl[i], wk4[i]);
            ws[O_CK + l*128 + e] = a;
        } else if (t < 170) {
            int f = t - 158;
            const float4* wa4 = (const float4*)(Wa + f*128);
            const float4* wq4 = (const float4*)wq_s;
            float a = 0.f;
            #pragma unroll 8
            for (int i = 0; i < 32; ++i) a += dot4(wa4[i], wq4[i]);
            wawq_s[f] = a;
        } else if (t == 170) {
            float a = bq[e];
            for (int d = 0; d < 128; ++d) a += ba[d]*wq_s[d];
            misc[0] = a;
        } else if (t >= 172 && t < 176) {
            int j = t - 172;
            const float4* wej = (const float4*)(We + j*128);
            const float4* wk4 = (const float4*)wk_s;
            float a = 0.f;
            #pragma unroll 8
            for (int i = 0; i < 32; ++i) a += dot4(wej[i], wk4[i]);
            ws[O_WEWK + j*128 + e] = a;
        }
        __syncthreads();

        // P2: wvop (512 jobs), qs, dbv, bop
        #pragma unroll
        for (int kk = 0; kk < 2; ++kk) {
            int job = t*2 + kk;
            int h = job & 3, d = job >> 2;
            const float4* wv4 = (const float4*)(Wv + d*128 + h*32);
            const float4* wc4 = (const float4*)(wop_s + h*32);
            float a = 0.f;
            #pragma unroll
            for (int i = 0; i < 8; ++i) a += dot4(wv4[i], wc4[i]);
            wvop[h*132 + d] = a;
        }
        if (t < 128) {
            float a = misc[0];
            const float* ag = agent + t*16;
            a += ag[2]*wawq_s[0];
            #pragma unroll
            for (int f = 1; f < 12; ++f) a += ag[4+f]*wawq_s[f];
            ws[O_QS + t*128 + e] = a * 0.17677669529663687f;
        } else if (t < 132) {
            int h = t-128;
            float a = 0.f;
            for (int c = 0; c < 32; ++c) a += bv[h*32+c]*wop_s[h*32+c];
            misc[1+h] = a;
        } else if (t == 132) {
            float a = bp[e];
            for (int c = 0; c < 128; ++c) a += bo[c]*wop_s[c];
            ws[O_BOP + e] = a;
        }
        __syncthreads();

        // P3: write transposed G row e (168 ushorts, zero-padded)
        unsigned short* GT = (unsigned short*)(ws + O_GT);
        if (t < 16) {
            int h = t >> 2, j = t & 3;
            const float4* wej = (const float4*)(We + j*128);
            const float4* wv4 = (const float4*)(wvop + h*132);
            float a = 0.f;
            #pragma unroll 8
            for (int i = 0; i < 32; ++i) a += dot4(wej[i], wv4[i]);
            GT[e*168 + t] = f2b(a);
        } else if (t < 136) {
            int r = t-16; int h = r/30, l = r - h*30;
            const float4* pl  = (const float4*)(pesum + l*132);
            const float4* wv4 = (const float4*)(wvop + h*132);
            float a = misc[1+h];
            #pragma unroll 8
            for (int i = 0; i < 32; ++i) a += dot4(pl[i], wv4[i]);
            GT[e*168 + t] = f2b(a);
        } else if (t < 168) {
            GT[e*168 + t] = 0;
        }
    }

    cg::this_grid().sync();

    // ---------------- MAIN: all 512 blocks ----------------
    const int bn = bid >> 2;
    const int m0 = (bid & 3) * MCH;
    const int b = bn >> 6;

    // M0: stage G_T (linear uint4 copy), zero-pad WcB, compute u/c
    {
        const uint4* src = (const uint4*)(ws + O_GT);
        uint4* dst = (uint4*)&G_T[0][0];
        for (int i = t; i < 2688; i += 256) dst[i] = src[i];
    }
    for (int i = t; i < 16*24; i += 256) {
        int m = i / 24, k = 136 + (i - m*24);
        WcB[m][k] = 0;
    }
    if (t < 136) {
        const float4* y;
        if (t < 16) {
            int h = t >> 2, j = t & 3;
            const float4* x = (const float4*)(ws + O_WEWK + j*128 + h*32);
            y = (const float4*)(ws + O_QS + bn*128 + h*32);
            float a = 0.f;
            #pragma unroll
            for (int i = 0; i < 8; ++i) a += dot4(x[i], y[i]);
            u_s[t] = a;
        } else {
            int r = t - 16; int h = r/30, l = r - h*30;
            const float4* x = (const float4*)(ws + O_CK + l*128 + h*32);
            y = (const float4*)(ws + O_QS + bn*128 + h*32);
            float a = 0.f;
            #pragma unroll
            for (int i = 0; i < 8; ++i) a += dot4(x[i], y[i]);
            c_s[r] = a;
        }
    }
    const float ax  = agent[bn*16+0], ay = agent[bn*16+1];
    const float as_ = agent[bn*16+3], ac = agent[bn*16+4];
    const float f1 = (ax==0.f && ay==0.f && as_==0.f && ac==0.f) ? 0.f : 1.f;
    __syncthreads();

    // M1: edges (bf16) + raw scores (f32)
    for (int job = t; job < MCH*30; job += 256) {
        int m = job / 30, l = job - m*30;
        const float* lp = lane + (size_t)((b*NM + m0 + m)*L_ + l)*4;
        float4 lv = *(const float4*)lp;
        float f2 = (lv.x==0.f && lv.y==0.f && lv.z==0.f && lv.w==0.f) ? 0.f : 1.f;
        float f = f1 * f2;
        float dx = lv.x - ax, dy = lv.y - ay;
        float rx = (ac*dx + as_*dy) * 0.1f * f;
        float ry = (ac*dy - as_*dx) * 0.1f * f;
        float rs = (lv.z*ac - lv.w*as_) * f;
        float rc = (lv.w*ac + lv.z*as_) * f;
        unsigned int p0 = (unsigned int)f2b(rx) | ((unsigned int)f2b(ry) << 16);
        unsigned int p1 = (unsigned int)f2b(rs) | ((unsigned int)f2b(rc) << 16);
        *(uint2*)&edge_s[m][l][0] = make_uint2(p0, p1);
        #pragma unroll
        for (int h = 0; h < 4; ++h) {
            Sc_s[m][h*30 + l] = rx*u_s[h*4+0] + ry*u_s[h*4+1] + rs*u_s[h*4+2]
                              + rc*u_s[h*4+3] + c_s[h*30+l];
        }
    }
    __syncthreads();

    // M2: softmax -> bf16 w into WcB[m][16+h*30+l]
    if (t < MCH*4) {
        int m = t >> 2, h = t & 3;
        float* s = &Sc_s[m][h*30];
        float mx = s[0];
        for (int l = 1; l < 30; ++l) mx = fmaxf(mx, s[l]);
        float sum = 0.f;
        for (int l = 0; l < 30; ++l) { float ev = __expf(s[l]-mx); s[l] = ev; sum += ev; }
        float inv = 1.f / sum;
        for (int l = 0; l < 30; ++l) WcB[m][16 + h*30 + l] = f2b(s[l]*inv);
    }
    __syncthreads();

    // M3: we4 -> bf16 into WcB[m][h*4+j]
    {
        int m = t >> 4, i = t & 15;
        int h = i >> 2, j = i & 3;
        float a = 0.f;
        for (int l = 0; l < 30; ++l)
            a += b2f(WcB[m][16 + h*30 + l]) * b2f(edge_s[m][l][j]);
        WcB[m][i] = f2b(a);
    }
    __syncthreads();

    // M4: OUT[16x128] = WcB[16x160] @ G[160x128] via MFMA, acc init = bop
    {
        const int lane_id = t & 63;
        const int wv = t >> 6;            // wave 0..3 -> 32 e's each
        const int frm = lane_id & 15;
        const int kg  = lane_id >> 4;
        const int e0 = wv*32 + frm;
        float bb0 = ws[O_BOP + e0];
        float bb1 = ws[O_BOP + e0 + 16];
        f32x4 acc0 = {bb0, bb0, bb0, bb0};
        f32x4 acc1 = {bb1, bb1, bb1, bb1};
        #pragma unroll
        for (int k0 = 0; k0 < 160; k0 += 32) {
            short8 a  = *(const short8*)&WcB[frm][k0 + kg*8];
            short8 g0 = *(const short8*)&G_T[e0][k0 + kg*8];
            short8 g1 = *(const short8*)&G_T[e0+16][k0 + kg*8];
            acc0 = __builtin_amdgcn_mfma_f32_16x16x32_bf16(a, g0, acc0, 0, 0, 0);
            acc1 = __builtin_amdgcn_mfma_f32_16x16x32_bf16(a, g1, acc1, 0, 0, 0);
        }
        float* ob = out + ((size_t)(bn*NM + m0))*128;
        #pragma unroll
        for (int r = 0; r < 4; ++r) {
            int m = kg*4 + r;
            ob[m*128 + e0]      = acc0[r];
            ob[m*128 + e0 + 16] = acc1[r];
        }
    }
}

extern "C" void kernel_launch(void* const* d_in, const int* in_sizes, int n_in,
                              void* d_out, int out_size, void* d_ws, size_t ws_size,
                              hipStream_t stream) {
    const float* agent = (const float*)d_in[0];
    const float* lane  = (const float*)d_in[1];
    const float* We = (const float*)d_in[2];
    const float* be = (const float*)d_in[3];
    const float* Wa = (const float*)d_in[4];
    const float* ba = (const float*)d_in[5];
    const float* pe = (const float*)d_in[6];
    const float* Wq = (const float*)d_in[7];
    const float* bq = (const float*)d_in[8];
    const float* Wk = (const float*)d_in[9];
    const float* bk = (const float*)d_in[10];
    const float* Wv = (const float*)d_in[11];
    const float* bv = (const float*)d_in[12];
    const float* Wo = (const float*)d_in[13];
    const float* bo = (const float*)d_in[14];
    const float* Wp = (const float*)d_in[15];
    const float* bp = (const float*)d_in[16];
    float* ws  = (float*)d_ws;
    float* out = (float*)d_out;

    void* args[] = {(void*)&agent, (void*)&lane, (void*)&We, (void*)&be,
                    (void*)&Wa, (void*)&ba, (void*)&pe, (void*)&Wq, (void*)&bq,
                    (void*)&Wk, (void*)&bk, (void*)&Wv, (void*)&bv,
                    (void*)&Wo, (void*)&bo, (void*)&Wp, (void*)&bp,
                    (void*)&ws, (void*)&out};
    hipLaunchCooperativeKernel((void*)k_fused, dim3(512), dim3(256), args, 0, stream);
}

// Round 4
// 26.703 us; speedup vs baseline: 3.5184x; 3.5184x over previous
//
#include <hip/hip_runtime.h>
#include <hip/hip_bf16.h>

#define L_ 30
#define NB 2
#define NN 64
#define NM 64
#define MCH 16

// ws float offsets
#define O_BOP  0        // 128
#define O_WEWK 128      // 4x128
#define O_CK   640      // 30x128
#define O_QS   4480     // 128x128 (q / sqrt(dh))
#define O_GT   20864    // ushort[128][168] transposed G (rows e, cols k), 10752 floats

typedef __attribute__((ext_vector_type(8))) short short8;
typedef __attribute__((ext_vector_type(4))) float f32x4;

__device__ __forceinline__ unsigned short f2b(float v) {
    union { float f; unsigned int u; } x; x.f = v;
    unsigned int u = x.u + 0x7FFFu + ((x.u >> 16) & 1u);
    return (unsigned short)(u >> 16);
}
__device__ __forceinline__ float b2f(unsigned short s) {
    union { unsigned int u; float f; } x; x.u = ((unsigned int)s) << 16; return x.f;
}
__device__ __forceinline__ float dot4(float4 a, float4 b) {
    return a.x*b.x + a.y*b.y + a.z*b.z + a.w*b.w;
}

// 128 blocks, one output column e each. Column-parallel precompute (see R2 notes).
__global__ __launch_bounds__(256)
void k_pre(const float* __restrict__ agent,
           const float* __restrict__ We,  const float* __restrict__ be,
           const float* __restrict__ Wa,  const float* __restrict__ ba,
           const float* __restrict__ pe,
           const float* __restrict__ Wq,  const float* __restrict__ bq,
           const float* __restrict__ Wk,  const float* __restrict__ bk,
           const float* __restrict__ Wv,  const float* __restrict__ bv,
           const float* __restrict__ Wo,  const float* __restrict__ bo,
           const float* __restrict__ Wp,  const float* __restrict__ bp,
           float* __restrict__ ws) {
    const int e = blockIdx.x;
    const int t = threadIdx.x;
    __shared__ __align__(16) float pb[5020];
    float* wp_s   = pb;           // 128
    float* wq_s   = pb + 128;     // 128
    float* wk_s   = pb + 256;     // 128
    float* wop_s  = pb + 384;     // 128
    float* wawq_s = pb + 512;     // 12
    float* misc   = pb + 524;     // [0]=bqq [1..4]=dbv
    float* pesum  = pb + 532;     // 30*132
    float* wvop   = pb + 4492;    // 4*132

    // P0: stage weight columns + pesum
    if (t < 128) { wp_s[t] = Wp[t*128+e]; wq_s[t] = Wq[t*128+e]; }
    else         { int d = t-128; wk_s[d] = Wk[d*128+e]; }
    for (int i = t; i < 30*128; i += 256) {
        int l = i >> 7, d = i & 127;
        pesum[l*132+d] = be[d] + pe[l*128+d];
    }
    __syncthreads();

    // P1: wop_col, Ck, WaWq, bqq, WeWk
    if (t < 128) {
        const float4* wo  = (const float4*)(Wo + t*128);
        const float4* wp4 = (const float4*)wp_s;
        float a = 0.f;
        #pragma unroll 8
        for (int i = 0; i < 32; ++i) a += dot4(wo[i], wp4[i]);
        wop_s[t] = a;
    } else if (t < 158) {
        int l = t - 128;
        const float4* pl  = (const float4*)(pesum + l*132);
        const float4* wk4 = (const float4*)wk_s;
        float a = bk[e];
        #pragma unroll 8
        for (int i = 0; i < 32; ++i) a += dot4(pl[i], wk4[i]);
        ws[O_CK + l*128 + e] = a;
    } else if (t < 170) {
        int f = t - 158;
        const float4* wa4 = (const float4*)(Wa + f*128);
        const float4* wq4 = (const float4*)wq_s;
        float a = 0.f;
        #pragma unroll 8
        for (int i = 0; i < 32; ++i) a += dot4(wa4[i], wq4[i]);
        wawq_s[f] = a;
    } else if (t == 170) {
        float a = bq[e];
        for (int d = 0; d < 128; ++d) a += ba[d]*wq_s[d];
        misc[0] = a;
    } else if (t >= 172 && t < 176) {
        int j = t - 172;
        const float4* wej = (const float4*)(We + j*128);
        const float4* wk4 = (const float4*)wk_s;
        float a = 0.f;
        #pragma unroll 8
        for (int i = 0; i < 32; ++i) a += dot4(wej[i], wk4[i]);
        ws[O_WEWK + j*128 + e] = a;
    }
    __syncthreads();

    // P2: wvop (512 jobs), qs, dbv, bop
    #pragma unroll
    for (int kk = 0; kk < 2; ++kk) {
        int job = t*2 + kk;
        int h = job & 3, d = job >> 2;
        const float4* wv4 = (const float4*)(Wv + d*128 + h*32);
        const float4* wc4 = (const float4*)(wop_s + h*32);
        float a = 0.f;
        #pragma unroll
        for (int i = 0; i < 8; ++i) a += dot4(wv4[i], wc4[i]);
        wvop[h*132 + d] = a;
    }
    if (t < 128) {
        float a = misc[0];
        const float* ag = agent + t*16;
        a += ag[2]*wawq_s[0];
        #pragma unroll
        for (int f = 1; f < 12; ++f) a += ag[4+f]*wawq_s[f];
        ws[O_QS + t*128 + e] = a * 0.17677669529663687f;
    } else if (t < 132) {
        int h = t-128;
        float a = 0.f;
        for (int c = 0; c < 32; ++c) a += bv[h*32+c]*wop_s[h*32+c];
        misc[1+h] = a;
    } else if (t == 132) {
        float a = bp[e];
        for (int c = 0; c < 128; ++c) a += bo[c]*wop_s[c];
        ws[O_BOP + e] = a;
    }
    __syncthreads();

    // P3: write transposed G row e (168 ushorts, zero-padded past 136)
    unsigned short* GT = (unsigned short*)(ws + O_GT);
    if (t < 16) {
        int h = t >> 2, j = t & 3;
        const float4* wej = (const float4*)(We + j*128);
        const float4* wv4 = (const float4*)(wvop + h*132);
        float a = 0.f;
        #pragma unroll 8
        for (int i = 0; i < 32; ++i) a += dot4(wej[i], wv4[i]);
        GT[e*168 + t] = f2b(a);
    } else if (t < 136) {
        int r = t-16; int h = r/30, l = r - h*30;
        const float4* pl  = (const float4*)(pesum + l*132);
        const float4* wv4 = (const float4*)(wvop + h*132);
        float a = misc[1+h];
        #pragma unroll 8
        for (int i = 0; i < 32; ++i) a += dot4(pl[i], wv4[i]);
        GT[e*168 + t] = f2b(a);
    } else if (t < 168) {
        GT[e*168 + t] = 0;
    }
}

// 512 blocks: bn = bid>>2, m-chunk of 16. MFMA epilogue reads G straight from L2.
__global__ __launch_bounds__(256)
void k_main(const float* __restrict__ agent, const float* __restrict__ lane,
            const float* __restrict__ ws, float* __restrict__ out) {

    __shared__ __align__(16) unsigned short WcB[16][168];    // bf16: [0..16) we4, [16..136) w, pad 0
    __shared__ __align__(16) float Sc_s[16][124];            // f32 raw scores [m][h*30+l]
    __shared__ __align__(16) unsigned short edge_s[MCH][30][4];
    __shared__ float u_s[16];
    __shared__ float c_s[120];

    const int t = threadIdx.x;
    const int bid = blockIdx.x;
    const int bn = bid >> 2;
    const int m0 = (bid & 3) * MCH;
    const int b = bn >> 6;

    // M0: zero-pad WcB tail, compute per-agent u (4x4) and c (4x30)
    for (int i = t; i < 16*24; i += 256) {
        int m = i / 24, k = 136 + (i - m*24);
        WcB[m][k] = 0;
    }
    if (t < 136) {
        if (t < 16) {
            int h = t >> 2, j = t & 3;
            const float4* x = (const float4*)(ws + O_WEWK + j*128 + h*32);
            const float4* y = (const float4*)(ws + O_QS + bn*128 + h*32);
            float a = 0.f;
            #pragma unroll
            for (int i = 0; i < 8; ++i) a += dot4(x[i], y[i]);
            u_s[t] = a;
        } else {
            int r = t - 16; int h = r/30, l = r - h*30;
            const float4* x = (const float4*)(ws + O_CK + l*128 + h*32);
            const float4* y = (const float4*)(ws + O_QS + bn*128 + h*32);
            float a = 0.f;
            #pragma unroll
            for (int i = 0; i < 8; ++i) a += dot4(x[i], y[i]);
            c_s[r] = a;
        }
    }
    const float ax  = agent[bn*16+0], ay = agent[bn*16+1];
    const float as_ = agent[bn*16+3], ac = agent[bn*16+4];
    const float f1 = (ax==0.f && ay==0.f && as_==0.f && ac==0.f) ? 0.f : 1.f;
    __syncthreads();

    // M1: edges (bf16) + raw scores (f32)
    for (int job = t; job < MCH*30; job += 256) {
        int m = job / 30, l = job - m*30;
        const float* lp = lane + (size_t)((b*NM + m0 + m)*L_ + l)*4;
        float4 lv = *(const float4*)lp;
        float f2 = (lv.x==0.f && lv.y==0.f && lv.z==0.f && lv.w==0.f) ? 0.f : 1.f;
        float f = f1 * f2;
        float dx = lv.x - ax, dy = lv.y - ay;
        float rx = (ac*dx + as_*dy) * 0.1f * f;
        float ry = (ac*dy - as_*dx) * 0.1f * f;
        float rs = (lv.z*ac - lv.w*as_) * f;
        float rc = (lv.w*ac + lv.z*as_) * f;
        unsigned int p0 = (unsigned int)f2b(rx) | ((unsigned int)f2b(ry) << 16);
        unsigned int p1 = (unsigned int)f2b(rs) | ((unsigned int)f2b(rc) << 16);
        *(uint2*)&edge_s[m][l][0] = make_uint2(p0, p1);
        #pragma unroll
        for (int h = 0; h < 4; ++h) {
            Sc_s[m][h*30 + l] = rx*u_s[h*4+0] + ry*u_s[h*4+1] + rs*u_s[h*4+2]
                              + rc*u_s[h*4+3] + c_s[h*30+l];
        }
    }
    __syncthreads();

    // M2: softmax -> bf16 w into WcB[m][16+h*30+l]
    if (t < MCH*4) {
        int m = t >> 2, h = t & 3;
        float* s = &Sc_s[m][h*30];
        float mx = s[0];
        for (int l = 1; l < 30; ++l) mx = fmaxf(mx, s[l]);
        float sum = 0.f;
        for (int l = 0; l < 30; ++l) { float ev = __expf(s[l]-mx); s[l] = ev; sum += ev; }
        float inv = 1.f / sum;
        for (int l = 0; l < 30; ++l) WcB[m][16 + h*30 + l] = f2b(s[l]*inv);
    }
    __syncthreads();

    // M3: we4 -> bf16 into WcB[m][h*4+j]   (256 jobs exactly)
    {
        int m = t >> 4, i = t & 15;
        int h = i >> 2, j = i & 3;
        float a = 0.f;
        for (int l = 0; l < 30; ++l)
            a += b2f(WcB[m][16 + h*30 + l]) * b2f(edge_s[m][l][j]);
        WcB[m][i] = f2b(a);
    }
    __syncthreads();

    // M4: OUT[16x128] = WcB[16x160] @ G[160x128] via MFMA; B-frags straight from L2
    {
        const unsigned short* GT = (const unsigned short*)(ws + O_GT);
        const int lane_id = t & 63;
        const int wv = t >> 6;            // wave -> e block of 32
        const int frm = lane_id & 15;
        const int kg  = lane_id >> 4;
        const int e0 = wv*32 + frm;
        float bb0 = ws[O_BOP + e0];
        float bb1 = ws[O_BOP + e0 + 16];
        f32x4 acc0 = {bb0, bb0, bb0, bb0};
        f32x4 acc1 = {bb1, bb1, bb1, bb1};
        #pragma unroll
        for (int k0 = 0; k0 < 160; k0 += 32) {
            short8 a  = *(const short8*)&WcB[frm][k0 + kg*8];
            short8 g0 = *(const short8*)&GT[(size_t)e0*168 + k0 + kg*8];
            short8 g1 = *(const short8*)&GT[(size_t)(e0+16)*168 + k0 + kg*8];
            acc0 = __builtin_amdgcn_mfma_f32_16x16x32_bf16(a, g0, acc0, 0, 0, 0);
            acc1 = __builtin_amdgcn_mfma_f32_16x16x32_bf16(a, g1, acc1, 0, 0, 0);
        }
        float* ob = out + ((size_t)(bn*NM + m0))*128;
        #pragma unroll
        for (int r = 0; r < 4; ++r) {
            int m = kg*4 + r;
            ob[m*128 + e0]      = acc0[r];
            ob[m*128 + e0 + 16] = acc1[r];
        }
    }
}

extern "C" void kernel_launch(void* const* d_in, const int* in_sizes, int n_in,
                              void* d_out, int out_size, void* d_ws, size_t ws_size,
                              hipStream_t stream) {
    const float* agent = (const float*)d_in[0];
    const float* lane  = (const float*)d_in[1];
    const float* We = (const float*)d_in[2];
    const float* be = (const float*)d_in[3];
    const float* Wa = (const float*)d_in[4];
    const float* ba = (const float*)d_in[5];
    const float* pe = (const float*)d_in[6];
    const float* Wq = (const float*)d_in[7];
    const float* bq = (const float*)d_in[8];
    const float* Wk = (const float*)d_in[9];
    const float* bk = (const float*)d_in[10];
    const float* Wv = (const float*)d_in[11];
    const float* bv = (const float*)d_in[12];
    const float* Wo = (const float*)d_in[13];
    const float* bo = (const float*)d_in[14];
    const float* Wp = (const float*)d_in[15];
    const float* bp = (const float*)d_in[16];
    float* ws  = (float*)d_ws;
    float* out = (float*)d_out;

    hipLaunchKernelGGL(k_pre, dim3(128), dim3(256), 0, stream,
                       agent, We, be, Wa, ba, pe, Wq, bq, Wk, bk, Wv, bv,
                       Wo, bo, Wp, bp, ws);
    hipLaunchKernelGGL(k_main, dim3(NB*NN*4), dim3(256), 0, stream,
                       agent, lane, ws, out);
}